// Round 2
// baseline (227.306 us; speedup 1.0000x reference)
//
#include <hip/hip_runtime.h>
#include <hip/hip_bf16.h>

#define S_ 512
#define B_ 32
#define D_ 1024
#define F_ 1024

typedef float f32x4 __attribute__((ext_vector_type(4)));
typedef short bf16x8 __attribute__((ext_vector_type(8)));

__device__ __forceinline__ unsigned short f2bf(float f) {
    __hip_bfloat16 h = __float2bfloat16(f);
    return *reinterpret_cast<unsigned short*>(&h);
}

__device__ __forceinline__ float sigmoidf_fast(float x) {
    // 1 / (1 + exp(-x)); exp via exp2
    float e = __builtin_amdgcn_exp2f(x * -1.44269504088896f);
    return __builtin_amdgcn_rcpf(1.0f + e);
}

// ---------------- Kernel V: v = x0 @ [w1|w2]^T + bias, into vbuf[B][2048] ----
// grid 256 blocks: fb = bid&31 (64 f each), ks = bid>>5 (128 k each)
__global__ __launch_bounds__(256) void vker(
    const float* __restrict__ x,
    const float* __restrict__ w1w, const float* __restrict__ w1b,
    const float* __restrict__ w2w, const float* __restrict__ w2b,
    float* __restrict__ vbuf)
{
    __shared__ float xs[B_][132];    // 32 x 128 (+4 pad)
    __shared__ float wst[64][132];   // 64 x 128 (+4 pad)
    int fb = blockIdx.x & 31;
    int ks = blockIdx.x >> 5;
    int k0 = ks * 128;
    int t  = threadIdx.x;
    const float* w = (fb < 16) ? w1w : w2w;
    int fbase = (fb < 16) ? fb * 64 : (fb - 16) * 64;

    #pragma unroll
    for (int i = 0; i < 4; ++i) {
        int q = t + 256 * i;
        int row = q >> 5, c4 = (q & 31) * 4;
        float4 v = *reinterpret_cast<const float4*>(x + (size_t)row * D_ + k0 + c4);
        *reinterpret_cast<float4*>(&xs[row][c4]) = v;
    }
    #pragma unroll
    for (int i = 0; i < 8; ++i) {
        int q = t + 256 * i;
        int row = q >> 5, c4 = (q & 31) * 4;
        float4 v = *reinterpret_cast<const float4*>(w + (size_t)(fbase + row) * D_ + k0 + c4);
        *reinterpret_cast<float4*>(&wst[row][c4]) = v;
    }
    __syncthreads();

    int b   = t >> 3;   // 0..31
    int fl0 = t & 7;
    float acc[8] = {0,0,0,0,0,0,0,0};
    for (int k4 = 0; k4 < 32; ++k4) {
        float4 xv = *reinterpret_cast<const float4*>(&xs[b][k4 * 4]);
        #pragma unroll
        for (int j = 0; j < 8; ++j) {
            float4 wv = *reinterpret_cast<const float4*>(&wst[fl0 + 8 * j][k4 * 4]);
            acc[j] += xv.x * wv.x + xv.y * wv.y + xv.z * wv.z + xv.w * wv.w;
        }
    }
    #pragma unroll
    for (int j = 0; j < 8; ++j) {
        int fg = fb * 64 + fl0 + 8 * j;   // 0..2047
        float v = acc[j];
        if (ks == 0) v += (fg < 1024) ? w1b[fg] : w2b[fg - 1024];
        atomicAdd(&vbuf[b * 2048 + fg], v);
    }
}

// ---------------- Kernel G: out[s,b,f] = sum_d Xbf16 * maskbf16 + model_b ----
#define BM 128
#define BN 128
#define BK 64
#define LDA 72   // bf16 elems per LDS row (64 + 8 pad) -> 144 B stride

__global__ __launch_bounds__(256) void gemm(
    const float* __restrict__ x,
    const float* __restrict__ mw, const float* __restrict__ mb,
    const float* __restrict__ vbuf,
    float* __restrict__ out)
{
    __shared__ __hip_bfloat16 As[BM * LDA];
    __shared__ __hip_bfloat16 Bs[BN * LDA];
    __shared__ float v2s[BN];

    int bid = blockIdx.x;
    int b   = bid >> 5;          // batch
    int t32 = bid & 31;
    int mt  = t32 & 3;           // s-tile (4)
    int nt  = t32 >> 2;          // f-tile (8)
    int s0 = mt * BM, n0 = nt * BN;

    int tid  = threadIdx.x;
    int lane = tid & 63, wid = tid >> 6;
    int wr = (wid >> 1) * 64;    // wave row offset in tile
    int wc = (wid & 1) * 64;     // wave col offset

    if (tid < BN) v2s[tid] = vbuf[b * 2048 + 1024 + n0 + tid];

    f32x4 acc[4][4] = {};

    const size_t xb = (size_t)b * D_;
    for (int kt = 0; kt < D_ / BK; ++kt) {
        int k0 = kt * BK;
        __syncthreads();   // prev compute done (also covers v2s preload)
        // stage A: x[s0+row, b, k0+c..c+3] -> bf16
        #pragma unroll
        for (int i = 0; i < 8; ++i) {
            int q = tid + 256 * i;
            int row = q >> 4;
            int c = (q & 15) * 4;
            float4 v = *reinterpret_cast<const float4*>(
                x + (size_t)(s0 + row) * (B_ * D_) + xb + k0 + c);
            unsigned long long pk =
                  (unsigned long long)f2bf(v.x)
                | ((unsigned long long)f2bf(v.y) << 16)
                | ((unsigned long long)f2bf(v.z) << 32)
                | ((unsigned long long)f2bf(v.w) << 48);
            *reinterpret_cast<unsigned long long*>(&As[row * LDA + c]) = pk;
        }
        // stage B: mask[k,n] = sigmoid(v1[k]*v2[n]) * model_w[n,k], stored [n][k]
        #pragma unroll
        for (int i = 0; i < 8; ++i) {
            int q = tid + 256 * i;
            int n = q >> 4;
            int c = (q & 15) * 4;
            float4 wv = *reinterpret_cast<const float4*>(mw + (size_t)(n0 + n) * D_ + k0 + c);
            float4 v1 = *reinterpret_cast<const float4*>(vbuf + b * 2048 + k0 + c);
            float v2  = v2s[n];
            unsigned long long pk =
                  (unsigned long long)f2bf(sigmoidf_fast(v1.x * v2) * wv.x)
                | ((unsigned long long)f2bf(sigmoidf_fast(v1.y * v2) * wv.y) << 16)
                | ((unsigned long long)f2bf(sigmoidf_fast(v1.z * v2) * wv.z) << 32)
                | ((unsigned long long)f2bf(sigmoidf_fast(v1.w * v2) * wv.w) << 48);
            *reinterpret_cast<unsigned long long*>(&Bs[n * LDA + c]) = pk;
        }
        __syncthreads();
        // compute: 2 k-halves x 16 MFMA
        #pragma unroll
        for (int kh = 0; kh < 2; ++kh) {
            int ko = (lane >> 4) * 8 + kh * 32;
            bf16x8 af[4], bfr[4];
            #pragma unroll
            for (int m2 = 0; m2 < 4; ++m2)
                af[m2] = *reinterpret_cast<const bf16x8*>(
                    &As[(wr + m2 * 16 + (lane & 15)) * LDA + ko]);
            #pragma unroll
            for (int n2 = 0; n2 < 4; ++n2)
                bfr[n2] = *reinterpret_cast<const bf16x8*>(
                    &Bs[(wc + n2 * 16 + (lane & 15)) * LDA + ko]);
            #pragma unroll
            for (int m2 = 0; m2 < 4; ++m2)
                #pragma unroll
                for (int n2 = 0; n2 < 4; ++n2)
                    acc[m2][n2] = __builtin_amdgcn_mfma_f32_16x16x32_bf16(
                        af[m2], bfr[n2], acc[m2][n2], 0, 0, 0);
        }
    }

    // epilogue
    int col = lane & 15, rg = (lane >> 4) * 4;
    float bias[4];
    #pragma unroll
    for (int n2 = 0; n2 < 4; ++n2) bias[n2] = mb[n0 + wc + n2 * 16 + col];
    #pragma unroll
    for (int m2 = 0; m2 < 4; ++m2) {
        #pragma unroll
        for (int n2 = 0; n2 < 4; ++n2) {
            #pragma unroll
            for (int r = 0; r < 4; ++r) {
                int srow = s0 + wr + m2 * 16 + rg + r;
                out[(size_t)srow * (B_ * F_) + b * F_ + n0 + wc + n2 * 16 + col]
                    = acc[m2][n2][r] + bias[n2];
            }
        }
    }
}

extern "C" void kernel_launch(void* const* d_in, const int* in_sizes, int n_in,
                              void* d_out, int out_size, void* d_ws, size_t ws_size,
                              hipStream_t stream) {
    const float* x   = (const float*)d_in[0];
    const float* w1w = (const float*)d_in[1];
    const float* w1b = (const float*)d_in[2];
    const float* w2w = (const float*)d_in[3];
    const float* w2b = (const float*)d_in[4];
    const float* mw  = (const float*)d_in[5];
    const float* mb  = (const float*)d_in[6];
    float* vbuf = (float*)d_ws;                 // [32][2048] f32 = 256 KB
    float* outp = (float*)d_out;

    hipMemsetAsync(vbuf, 0, B_ * 2048 * sizeof(float), stream);
    vker<<<256, 256, 0, stream>>>(x, w1w, w1b, w2w, w2b, vbuf);
    gemm<<<32 * 4 * 8, 256, 0, stream>>>(x, mw, mb, vbuf, outp);
}